// Round 7
// baseline (537.626 us; speedup 1.0000x reference)
//
#include <hip/hip_runtime.h>

// Internal pipeline bf16 (ushort bits); external inputs/outputs float32.
typedef __attribute__((ext_vector_type(8))) short bf16x8;
typedef __attribute__((ext_vector_type(4))) float f32x4;

__device__ __forceinline__ float b2f(ushort b) {
    union { unsigned int u; float f; } x;
    x.u = ((unsigned int)b) << 16;
    return x.f;
}
__device__ __forceinline__ ushort f2b(float f) {
    union { float f; unsigned int u; } x;
    x.f = f;
    unsigned int r = x.u + 0x7fffu + ((x.u >> 16) & 1u);
    return (ushort)(r >> 16);
}
__device__ __forceinline__ int4 pack8(float4 a, float4 b) {
    union { int4 v; ushort u[8]; } r;
    r.u[0] = f2b(a.x); r.u[1] = f2b(a.y); r.u[2] = f2b(a.z); r.u[3] = f2b(a.w);
    r.u[4] = f2b(b.x); r.u[5] = f2b(b.y); r.u[6] = f2b(b.z); r.u[7] = f2b(b.w);
    return r.v;
}
__device__ __forceinline__ void gl2lds16(const ushort* g, ushort* l) {
    __builtin_amdgcn_global_load_lds(
        (const __attribute__((address_space(1))) void*)g,
        (__attribute__((address_space(3))) void*)l, 16, 0, 0);
}

// ---------------------------------------------------------------------------
// GEMM 128x128 tile (N>=1152): BK=32 chunks, K-loop unrolled x2 (one barrier
// pair per 64 K-elems). 4 waves (2x2), 4x4 frags/wave. K%64==0.
// ---------------------------------------------------------------------------
__global__ __launch_bounds__(256) void gemm_bt(
    const ushort* __restrict__ A, const ushort* __restrict__ Bt,
    ushort* __restrict__ C, const float* __restrict__ bias,
    const ushort* __restrict__ resb, const float* __restrict__ resf,
    int M, int N, int K, int relu)
{
    __shared__ __align__(16) ushort As[2][128 * 32];   // 16 KB
    __shared__ __align__(16) ushort Bs[2][128 * 32];   // 16 KB
    const int tid  = threadIdx.x;
    const int wave = tid >> 6, lane = tid & 63;
    const int wm = wave >> 1, wn = wave & 1;
    const int qd = lane >> 4, lc = lane & 15;
    const int row0 = blockIdx.y * 128, col0 = blockIdx.x * 128;
    const int sr = lane >> 2;          // 0..15
    const int sc = (lane & 3) * 8;     // 0,8,16,24

    const ushort* Ag  = A  + (size_t)(row0 + wave * 32 + sr) * K + sc;
    const ushort* Ag2 = Ag + (size_t)16 * K;
    const ushort* Bg  = Bt + (size_t)(col0 + wave * 32 + sr) * K + sc;
    const ushort* Bg2 = Bg + (size_t)16 * K;

    f32x4 acc[4][4];
#pragma unroll
    for (int i = 0; i < 4; i++)
#pragma unroll
        for (int j = 0; j < 4; j++) acc[i][j] = 0.0f;

    for (int k0 = 0; k0 < K; k0 += 64) {
        gl2lds16(Ag  + k0,      &As[0][wave * 1024]);
        gl2lds16(Ag2 + k0,      &As[0][wave * 1024 + 512]);
        gl2lds16(Bg  + k0,      &Bs[0][wave * 1024]);
        gl2lds16(Bg2 + k0,      &Bs[0][wave * 1024 + 512]);
        gl2lds16(Ag  + k0 + 32, &As[1][wave * 1024]);
        gl2lds16(Ag2 + k0 + 32, &As[1][wave * 1024 + 512]);
        gl2lds16(Bg  + k0 + 32, &Bs[1][wave * 1024]);
        gl2lds16(Bg2 + k0 + 32, &Bs[1][wave * 1024 + 512]);
        __syncthreads();

#pragma unroll
        for (int c = 0; c < 2; c++) {
            bf16x8 af[4], bfr[4];
#pragma unroll
            for (int mi = 0; mi < 4; mi++)
                af[mi] = *(const bf16x8*)&As[c][(wm * 64 + mi * 16 + lc) * 32 + qd * 8];
#pragma unroll
            for (int ni = 0; ni < 4; ni++)
                bfr[ni] = *(const bf16x8*)&Bs[c][(wn * 64 + ni * 16 + lc) * 32 + qd * 8];
#pragma unroll
            for (int mi = 0; mi < 4; mi++)
#pragma unroll
                for (int ni = 0; ni < 4; ni++)
                    acc[mi][ni] = __builtin_amdgcn_mfma_f32_16x16x32_bf16(
                        af[mi], bfr[ni], acc[mi][ni], 0, 0, 0);
        }
        __syncthreads();
    }

#pragma unroll
    for (int mi = 0; mi < 4; mi++) {
#pragma unroll
        for (int r = 0; r < 4; r++) {
            int grow = row0 + wm * 64 + mi * 16 + qd * 4 + r;
#pragma unroll
            for (int ni = 0; ni < 4; ni++) {
                int gcol = col0 + wn * 64 + ni * 16 + lc;
                float v = acc[mi][ni][r];
                if (bias) v += bias[gcol];
                if (resb) v += b2f(resb[(size_t)grow * N + gcol]);
                if (resf) v += resf[(size_t)grow * N + gcol];
                if (relu) v = fmaxf(v, 0.0f);
                C[(size_t)grow * N + gcol] = f2b(v);
            }
        }
    }
}

// ---------------------------------------------------------------------------
// GEMM 128x64 tile (N<=768): BK=32 chunks, unrolled x2. 4 waves on M,
// 2x4 frags/wave. K%64==0.
// ---------------------------------------------------------------------------
__global__ __launch_bounds__(256) void gemm_n64(
    const ushort* __restrict__ A, const ushort* __restrict__ Bt,
    ushort* __restrict__ C, const float* __restrict__ bias,
    const ushort* __restrict__ resb, const float* __restrict__ resf,
    int M, int N, int K, int relu)
{
    __shared__ __align__(16) ushort As[2][128 * 32];   // 16 KB
    __shared__ __align__(16) ushort Bs[2][64 * 32];    // 8 KB
    const int tid  = threadIdx.x;
    const int wave = tid >> 6, lane = tid & 63;
    const int qd = lane >> 4, lc = lane & 15;
    const int row0 = blockIdx.y * 128, col0 = blockIdx.x * 64;
    const int sr = lane >> 2;
    const int sc = (lane & 3) * 8;

    const ushort* Ag  = A  + (size_t)(row0 + wave * 32 + sr) * K + sc;
    const ushort* Ag2 = Ag + (size_t)16 * K;
    const ushort* Bg  = Bt + (size_t)(col0 + wave * 16 + sr) * K + sc;

    f32x4 acc[2][4];
#pragma unroll
    for (int i = 0; i < 2; i++)
#pragma unroll
        for (int j = 0; j < 4; j++) acc[i][j] = 0.0f;

    for (int k0 = 0; k0 < K; k0 += 64) {
        gl2lds16(Ag  + k0,      &As[0][wave * 1024]);
        gl2lds16(Ag2 + k0,      &As[0][wave * 1024 + 512]);
        gl2lds16(Bg  + k0,      &Bs[0][wave * 512]);
        gl2lds16(Ag  + k0 + 32, &As[1][wave * 1024]);
        gl2lds16(Ag2 + k0 + 32, &As[1][wave * 1024 + 512]);
        gl2lds16(Bg  + k0 + 32, &Bs[1][wave * 512]);
        __syncthreads();

#pragma unroll
        for (int c = 0; c < 2; c++) {
            bf16x8 af[2], bfr[4];
#pragma unroll
            for (int mi = 0; mi < 2; mi++)
                af[mi] = *(const bf16x8*)&As[c][(wave * 32 + mi * 16 + lc) * 32 + qd * 8];
#pragma unroll
            for (int ni = 0; ni < 4; ni++)
                bfr[ni] = *(const bf16x8*)&Bs[c][(ni * 16 + lc) * 32 + qd * 8];
#pragma unroll
            for (int mi = 0; mi < 2; mi++)
#pragma unroll
                for (int ni = 0; ni < 4; ni++)
                    acc[mi][ni] = __builtin_amdgcn_mfma_f32_16x16x32_bf16(
                        af[mi], bfr[ni], acc[mi][ni], 0, 0, 0);
        }
        __syncthreads();
    }

#pragma unroll
    for (int mi = 0; mi < 2; mi++) {
#pragma unroll
        for (int r = 0; r < 4; r++) {
            int grow = row0 + wave * 32 + mi * 16 + qd * 4 + r;
#pragma unroll
            for (int ni = 0; ni < 4; ni++) {
                int gcol = col0 + ni * 16 + lc;
                float v = acc[mi][ni][r];
                if (bias) v += bias[gcol];
                if (resb) v += b2f(resb[(size_t)grow * N + gcol]);
                if (resf) v += resf[(size_t)grow * N + gcol];
                if (relu) v = fmaxf(v, 0.0f);
                C[(size_t)grow * N + gcol] = f2b(v);
            }
        }
    }
}

// ---------------------------------------------------------------------------
// Fused q2 + kv2 GEMM (both K=384, M=16384, no residual/relu).
// Grid (18,128): bx<6 -> C1[.,384] = A1*B1t; else C2[.,768] = A2*B2t.
// Same body as gemm_n64 with per-block param select.
// ---------------------------------------------------------------------------
__global__ __launch_bounds__(256) void gemm_dual(
    const ushort* __restrict__ A1, const ushort* __restrict__ B1t,
    ushort* __restrict__ C1, const float* __restrict__ bias1, int N1,
    const ushort* __restrict__ A2, const ushort* __restrict__ B2t,
    ushort* __restrict__ C2, const float* __restrict__ bias2, int N2,
    int split, int K)
{
    __shared__ __align__(16) ushort As[2][128 * 32];
    __shared__ __align__(16) ushort Bs[2][64 * 32];
    const int tid  = threadIdx.x;
    const int wave = tid >> 6, lane = tid & 63;
    const int qd = lane >> 4, lc = lane & 15;
    const bool first = (int)blockIdx.x < split;
    const ushort* A  = first ? A1 : A2;
    const ushort* Bt = first ? B1t : B2t;
    ushort* C        = first ? C1 : C2;
    const float* bias = first ? bias1 : bias2;
    const int N      = first ? N1 : N2;
    const int col0   = (first ? blockIdx.x : blockIdx.x - split) * 64;
    const int row0   = blockIdx.y * 128;
    const int sr = lane >> 2;
    const int sc = (lane & 3) * 8;

    const ushort* Ag  = A  + (size_t)(row0 + wave * 32 + sr) * K + sc;
    const ushort* Ag2 = Ag + (size_t)16 * K;
    const ushort* Bg  = Bt + (size_t)(col0 + wave * 16 + sr) * K + sc;

    f32x4 acc[2][4];
#pragma unroll
    for (int i = 0; i < 2; i++)
#pragma unroll
        for (int j = 0; j < 4; j++) acc[i][j] = 0.0f;

    for (int k0 = 0; k0 < K; k0 += 64) {
        gl2lds16(Ag  + k0,      &As[0][wave * 1024]);
        gl2lds16(Ag2 + k0,      &As[0][wave * 1024 + 512]);
        gl2lds16(Bg  + k0,      &Bs[0][wave * 512]);
        gl2lds16(Ag  + k0 + 32, &As[1][wave * 1024]);
        gl2lds16(Ag2 + k0 + 32, &As[1][wave * 1024 + 512]);
        gl2lds16(Bg  + k0 + 32, &Bs[1][wave * 512]);
        __syncthreads();

#pragma unroll
        for (int c = 0; c < 2; c++) {
            bf16x8 af[2], bfr[4];
#pragma unroll
            for (int mi = 0; mi < 2; mi++)
                af[mi] = *(const bf16x8*)&As[c][(wave * 32 + mi * 16 + lc) * 32 + qd * 8];
#pragma unroll
            for (int ni = 0; ni < 4; ni++)
                bfr[ni] = *(const bf16x8*)&Bs[c][(ni * 16 + lc) * 32 + qd * 8];
#pragma unroll
            for (int mi = 0; mi < 2; mi++)
#pragma unroll
                for (int ni = 0; ni < 4; ni++)
                    acc[mi][ni] = __builtin_amdgcn_mfma_f32_16x16x32_bf16(
                        af[mi], bfr[ni], acc[mi][ni], 0, 0, 0);
        }
        __syncthreads();
    }

#pragma unroll
    for (int mi = 0; mi < 2; mi++) {
#pragma unroll
        for (int r = 0; r < 4; r++) {
            int grow = row0 + wave * 32 + mi * 16 + qd * 4 + r;
#pragma unroll
            for (int ni = 0; ni < 4; ni++) {
                int gcol = col0 + ni * 16 + lc;
                float v = acc[mi][ni][r] + bias[gcol];
                C[(size_t)grow * N + gcol] = f2b(v);
            }
        }
    }
}

// ---------------------------------------------------------------------------
// Attention: one block per (b, h, 64-row q tile). Causal tril + softmax.
// ---------------------------------------------------------------------------
__global__ __launch_bounds__(256) void attn(
    const ushort* __restrict__ q, int qstr,
    const ushort* __restrict__ k, int kstr,
    const ushort* __restrict__ v, int vstr,
    ushort* __restrict__ out)
{
    __shared__ __align__(16) ushort Qs[64 * 72];
    __shared__ __align__(16) ushort Kc[64 * 72];
    __shared__ __align__(16) ushort Vc[64 * 72];
    __shared__ __align__(16) ushort Ps[64 * 264];

    const int tid = threadIdx.x;
    const int wave = tid >> 6, lane = tid & 63;
    const int qd = lane >> 4, lc = lane & 15;
    const int b = blockIdx.z, h = blockIdx.y, t0 = blockIdx.x * 64;
    const int hc = h * 64;
    const float scale = 0.051031036307982884f;  // 384^-0.5 (faithful: E, not HS)

    {
        int r = tid >> 2, c = (tid & 3) * 16;
        int4 q0 = *(const int4*)&q[(size_t)(b * 256 + t0 + r) * qstr + hc + c];
        int4 q1 = *(const int4*)&q[(size_t)(b * 256 + t0 + r) * qstr + hc + c + 8];
        *(int4*)&Qs[r * 72 + c] = q0;
        *(int4*)&Qs[r * 72 + c + 8] = q1;
    }

    f32x4 accS[16];
#pragma unroll
    for (int j = 0; j < 16; j++) accS[j] = 0.0f;

    for (int uc = 0; uc < 4; uc++) {
        int r = tid >> 2, c = (tid & 3) * 16;
        int4 k0v = *(const int4*)&k[(size_t)(b * 256 + uc * 64 + r) * kstr + hc + c];
        int4 k1v = *(const int4*)&k[(size_t)(b * 256 + uc * 64 + r) * kstr + hc + c + 8];
        __syncthreads();
        *(int4*)&Kc[r * 72 + c] = k0v;
        *(int4*)&Kc[r * 72 + c + 8] = k1v;
        __syncthreads();
#pragma unroll
        for (int s0 = 0; s0 < 64; s0 += 32) {
            bf16x8 a = *(const bf16x8*)&Qs[(wave * 16 + lc) * 72 + s0 + qd * 8];
#pragma unroll
            for (int ni = 0; ni < 4; ni++) {
                bf16x8 bb = *(const bf16x8*)&Kc[(ni * 16 + lc) * 72 + s0 + qd * 8];
                accS[uc * 4 + ni] =
                    __builtin_amdgcn_mfma_f32_16x16x32_bf16(a, bb, accS[uc * 4 + ni], 0, 0, 0);
            }
        }
    }

#pragma unroll
    for (int rr = 0; rr < 4; rr++) {
        int t = t0 + wave * 16 + qd * 4 + rr;
        float pv[16];
        float mx = -3.0e38f;
#pragma unroll
        for (int j = 0; j < 16; j++) {
            int u = (j >> 2) * 64 + (j & 3) * 16 + lc;
            float s = accS[j][rr] * scale;
            s = (u <= t) ? s : -3.0e38f;
            pv[j] = s;
            mx = fmaxf(mx, s);
        }
#pragma unroll
        for (int m = 1; m < 16; m <<= 1) mx = fmaxf(mx, __shfl_xor(mx, m, 16));
        float sum = 0.0f;
#pragma unroll
        for (int j = 0; j < 16; j++) { float p = __expf(pv[j] - mx); pv[j] = p; sum += p; }
#pragma unroll
        for (int m = 1; m < 16; m <<= 1) sum += __shfl_xor(sum, m, 16);
        float inv = 1.0f / sum;
#pragma unroll
        for (int j = 0; j < 16; j++) {
            int u = (j >> 2) * 64 + (j & 3) * 16 + lc;
            Ps[(wave * 16 + qd * 4 + rr) * 264 + u] = f2b(pv[j] * inv);
        }
    }

    f32x4 accO[4];
#pragma unroll
    for (int j = 0; j < 4; j++) accO[j] = 0.0f;
    for (int uc = 0; uc < 4; uc++) {
        int r = tid >> 2, s0 = (tid & 3) * 16;
        int4 v0 = *(const int4*)&v[(size_t)(b * 256 + uc * 64 + r) * vstr + hc + s0];
        int4 v1 = *(const int4*)&v[(size_t)(b * 256 + uc * 64 + r) * vstr + hc + s0 + 8];
        __syncthreads();
        {
            const ushort* t0p = (const ushort*)&v0;
            const ushort* t1p = (const ushort*)&v1;
#pragma unroll
            for (int j = 0; j < 8; j++) Vc[(s0 + j) * 72 + r] = t0p[j];
#pragma unroll
            for (int j = 0; j < 8; j++) Vc[(s0 + 8 + j) * 72 + r] = t1p[j];
        }
        __syncthreads();
#pragma unroll
        for (int u0 = 0; u0 < 64; u0 += 32) {
            bf16x8 a = *(const bf16x8*)&Ps[(wave * 16 + lc) * 264 + uc * 64 + u0 + qd * 8];
#pragma unroll
            for (int ni = 0; ni < 4; ni++) {
                bf16x8 bb = *(const bf16x8*)&Vc[(ni * 16 + lc) * 72 + u0 + qd * 8];
                accO[ni] = __builtin_amdgcn_mfma_f32_16x16x32_bf16(a, bb, accO[ni], 0, 0, 0);
            }
        }
    }

#pragma unroll
    for (int ni = 0; ni < 4; ni++)
#pragma unroll
        for (int rr = 0; rr < 4; rr++) {
            int t = t0 + wave * 16 + qd * 4 + rr;
            out[(size_t)(b * 256 + t) * 384 + hc + ni * 16 + lc] = f2b(accO[ni][rr]);
        }
}

// ---------------------------------------------------------------------------
// LayerNorm rows of 384. One wave per row. g/be f32; in bf16; out bf16 or f32.
// ---------------------------------------------------------------------------
__global__ __launch_bounds__(256) void lnorm(
    const ushort* __restrict__ in, const float* __restrict__ g,
    const float* __restrict__ be, ushort* __restrict__ outb,
    float* __restrict__ outf)
{
    const int wave = threadIdx.x >> 6, lane = threadIdx.x & 63;
    const int row = blockIdx.x * 4 + wave;
    const ushort* r = in + (size_t)row * 384;
    float x[6], s1 = 0.0f, s2 = 0.0f;
#pragma unroll
    for (int j = 0; j < 6; j++) {
        x[j] = b2f(r[j * 64 + lane]);
        s1 += x[j]; s2 += x[j] * x[j];
    }
#pragma unroll
    for (int m = 1; m < 64; m <<= 1) {
        s1 += __shfl_xor(s1, m, 64);
        s2 += __shfl_xor(s2, m, 64);
    }
    float mean = s1 * (1.0f / 384.0f);
    float var  = s2 * (1.0f / 384.0f) - mean * mean;
    float rstd = rsqrtf(var + 1e-5f);
#pragma unroll
    for (int j = 0; j < 6; j++) {
        float y = (x[j] - mean) * rstd * g[j * 64 + lane] + be[j * 64 + lane];
        if (outb) outb[(size_t)row * 384 + j * 64 + lane] = f2b(y);
        if (outf) outf[(size_t)row * 384 + j * 64 + lane] = y;
    }
}

// f32 -> bf16 elementwise, 8 per thread (n = grid*256*8 exactly)
__global__ __launch_bounds__(256) void f32cvt(const float* __restrict__ in,
                                             ushort* __restrict__ out)
{
    size_t i = ((size_t)blockIdx.x * 256 + threadIdx.x) * 8;
    float4 a = *(const float4*)(in + i);
    float4 b = *(const float4*)(in + i + 4);
    *(int4*)(out + i) = pack8(a, b);
}

// Tiled transpose+cvt: in [R,C] f32 -> out [C,R] bf16. Grid (C/32, R/32).
__global__ __launch_bounds__(256) void transp_t(
    const float* __restrict__ in, ushort* __restrict__ out, int R, int C)
{
    __shared__ float t[32][33];
    const int tx = threadIdx.x & 31, ty = threadIdx.x >> 5;  // 32x8
    const int c0 = blockIdx.x * 32, r0 = blockIdx.y * 32;
#pragma unroll
    for (int i = 0; i < 32; i += 8)
        t[ty + i][tx] = in[(size_t)(r0 + ty + i) * C + c0 + tx];
    __syncthreads();
#pragma unroll
    for (int i = 0; i < 32; i += 8)
        out[(size_t)(c0 + ty + i) * R + r0 + tx] = f2b(t[tx][ty + i]);
}

// QKV pack, tiled: per (seg,h) transpose [E=384,HS=64] f32 -> Wt rows. Grid (12,2,18).
__global__ __launch_bounds__(256) void pack_qkv_t(
    const float* __restrict__ wq, const float* __restrict__ wk,
    const float* __restrict__ wv, ushort* __restrict__ Wt)
{
    __shared__ float t[32][33];
    const int tx = threadIdx.x & 31, ty = threadIdx.x >> 5;
    const int e0 = blockIdx.x * 32, s0 = blockIdx.y * 32;
    const int z = blockIdx.z, seg = z / 6, h = z - seg * 6;
    const float* w = (seg == 0) ? wq : (seg == 1) ? wk : wv;
    const float* wh = w + (size_t)h * 384 * 64;
#pragma unroll
    for (int i = 0; i < 32; i += 8)
        t[ty + i][tx] = wh[(size_t)(e0 + ty + i) * 64 + s0 + tx];
    __syncthreads();
    const int nbase = seg * 384 + h * 64 + s0;
#pragma unroll
    for (int i = 0; i < 32; i += 8)
        Wt[(size_t)(nbase + ty + i) * 384 + e0 + tx] = f2b(t[tx][ty + i]);
}

// bias concat: b1 = [q1|k1|v1], b2 = [q2|k2|v2] (f32, 1152 each). Grid 9.
__global__ __launch_bounds__(256) void biaspack(
    const float* __restrict__ q1, const float* __restrict__ k1, const float* __restrict__ v1,
    const float* __restrict__ q2, const float* __restrict__ k2, const float* __restrict__ v2,
    float* __restrict__ b1, float* __restrict__ b2)
{
    int i = blockIdx.x * 256 + threadIdx.x;
    if (i >= 2304) return;
    int grp = i / 1152, r = i - grp * 1152;
    int seg = r / 384, nn = r - seg * 384;
    const float* src = grp == 0 ? (seg == 0 ? q1 : seg == 1 ? k1 : v1)
                                : (seg == 0 ? q2 : seg == 1 ? k2 : v2);
    (grp == 0 ? b1 : b2)[r] = src[nn];
}

// ---------------------------------------------------------------------------
extern "C" void kernel_launch(void* const* d_in, const int* in_sizes, int n_in,
                              void* d_out, int out_size, void* d_ws, size_t ws_size,
                              hipStream_t stream)
{
    const float* enc = (const float*)d_in[0];
    const float* x   = (const float*)d_in[1];
    const float* s1wq = (const float*)d_in[2];  const float* s1bq = (const float*)d_in[3];
    const float* s1wk = (const float*)d_in[4];  const float* s1bk = (const float*)d_in[5];
    const float* s1wv = (const float*)d_in[6];  const float* s1bv = (const float*)d_in[7];
    const float* s1pw = (const float*)d_in[8];  const float* s1pb = (const float*)d_in[9];
    const float* s2wq = (const float*)d_in[10]; const float* s2bq = (const float*)d_in[11];
    const float* s2wk = (const float*)d_in[12]; const float* s2bk = (const float*)d_in[13];
    const float* s2wv = (const float*)d_in[14]; const float* s2bv = (const float*)d_in[15];
    const float* s2pw = (const float*)d_in[16]; const float* s2pb = (const float*)d_in[17];
    const float* fw1 = (const float*)d_in[18];  const float* fb1 = (const float*)d_in[19];
    const float* fw2 = (const float*)d_in[20];  const float* fb2 = (const float*)d_in[21];
    const float* g1 = (const float*)d_in[22];   const float* be1 = (const float*)d_in[23];
    const float* g2 = (const float*)d_in[24];   const float* be2 = (const float*)d_in[25];
    const float* g3 = (const float*)d_in[26];   const float* be3 = (const float*)d_in[27];

    if (ws_size < 80216064u) return;  // proven-available scratch size

    ushort* wsp = (ushort*)d_ws;           // ushort-element offsets
    ushort* qkv1 = wsp;
    ushort* q2   = wsp;
    ushort* kv2  = wsp + 6291456;
    ushort* h1   = wsp;
    ushort* att  = wsp + 18874368;         // [16384,384]; xb shares (dead before attn1)
    ushort* xb   = wsp + 18874368;
    ushort* tmp  = wsp + 25165824;         // [16384,384] pre-LN
    ushort* o1b  = wsp + 31457280;         // [16384,384]
    ushort* W1   = wsp + 37748736;         // [1152,384]
    ushort* W2   = W1 + 442368;
    ushort* pw1t = W2 + 442368;            // [384,384]
    ushort* pw2t = pw1t + 147456;          // [384,384]
    ushort* w1t  = pw2t + 147456;          // [1536,384]
    ushort* w2t  = w1t + 589824;           // [384,1536]

    ushort* encb = (ushort*)d_out;         // dead after kv2 gemm
    ushort* o2b  = (ushort*)d_out;
    float* bias1 = (float*)((ushort*)d_out + 6291456);
    float* bias2 = bias1 + 1152;

    // prep
    f32cvt<<<dim3(3072), dim3(256), 0, stream>>>(x, xb);
    f32cvt<<<dim3(3072), dim3(256), 0, stream>>>(enc, encb);
    pack_qkv_t<<<dim3(12, 2, 18), dim3(256), 0, stream>>>(s1wq, s1wk, s1wv, W1);
    pack_qkv_t<<<dim3(12, 2, 18), dim3(256), 0, stream>>>(s2wq, s2wk, s2wv, W2);
    biaspack<<<dim3(9), dim3(256), 0, stream>>>(s1bq, s1bk, s1bv, s2bq, s2bk, s2bv, bias1, bias2);
    transp_t<<<dim3(12, 12), dim3(256), 0, stream>>>(s1pw, pw1t, 384, 384);
    transp_t<<<dim3(12, 12), dim3(256), 0, stream>>>(s2pw, pw2t, 384, 384);
    transp_t<<<dim3(48, 12), dim3(256), 0, stream>>>(fw1, w1t, 384, 1536);
    transp_t<<<dim3(12, 48), dim3(256), 0, stream>>>(fw2, w2t, 1536, 384);

    // stage 1
    gemm_bt<<<dim3(9, 128), dim3(256), 0, stream>>>(xb, W1, qkv1, bias1, nullptr, nullptr, 16384, 1152, 384, 0);
    attn<<<dim3(4, 6, 64), dim3(256), 0, stream>>>(qkv1, 1152, qkv1 + 384, 1152, qkv1 + 768, 1152, att);
    gemm_n64<<<dim3(6, 128), dim3(256), 0, stream>>>(att, pw1t, tmp, s1pb, nullptr, x, 16384, 384, 384, 0);
    lnorm<<<dim3(4096), dim3(256), 0, stream>>>(tmp, g1, be1, o1b, nullptr);

    // stage 2 (q2 + kv2 fused into one dispatch)
    gemm_dual<<<dim3(18, 128), dim3(256), 0, stream>>>(
        o1b, W2, q2, bias2, 384,
        encb, W2 + 147456, kv2, bias2 + 384, 768, 6, 384);
    attn<<<dim3(4, 6, 64), dim3(256), 0, stream>>>(q2, 384, kv2, 768, kv2 + 384, 768, att);
    gemm_n64<<<dim3(6, 128), dim3(256), 0, stream>>>(att, pw2t, tmp, s2pb, o1b, nullptr, 16384, 384, 384, 0);
    lnorm<<<dim3(4096), dim3(256), 0, stream>>>(tmp, g2, be2, o2b, nullptr);

    // stage 3
    gemm_bt<<<dim3(12, 128), dim3(256), 0, stream>>>(o2b, w1t, h1, fb1, nullptr, nullptr, 16384, 1536, 384, 1);
    gemm_n64<<<dim3(6, 128), dim3(256), 0, stream>>>(h1, w2t, tmp, fb2, o2b, nullptr, 16384, 384, 1536, 0);
    lnorm<<<dim3(4096), dim3(256), 0, stream>>>(tmp, g3, be3, nullptr, (float*)d_out);
}

// Round 8
// 498.699 us; speedup vs baseline: 1.0781x; 1.0781x over previous
//
#include <hip/hip_runtime.h>

// Internal pipeline bf16 (ushort bits); external inputs/outputs float32.
typedef __attribute__((ext_vector_type(8))) short bf16x8;
typedef __attribute__((ext_vector_type(4))) float f32x4;

__device__ __forceinline__ float b2f(ushort b) {
    union { unsigned int u; float f; } x;
    x.u = ((unsigned int)b) << 16;
    return x.f;
}
__device__ __forceinline__ ushort f2b(float f) {
    union { float f; unsigned int u; } x;
    x.f = f;
    unsigned int r = x.u + 0x7fffu + ((x.u >> 16) & 1u);
    return (ushort)(r >> 16);
}
__device__ __forceinline__ int4 pack8(float4 a, float4 b) {
    union { int4 v; ushort u[8]; } r;
    r.u[0] = f2b(a.x); r.u[1] = f2b(a.y); r.u[2] = f2b(a.z); r.u[3] = f2b(a.w);
    r.u[4] = f2b(b.x); r.u[5] = f2b(b.y); r.u[6] = f2b(b.z); r.u[7] = f2b(b.w);
    return r.v;
}

// ---------------------------------------------------------------------------
// GEMM 128x128 tile (N>=1152): BK=32, register-staged software pipeline.
// Next chunk's global loads issue before the compute barrier -> latency
// overlaps MFMA (no vmcnt drain needed for reg loads at barriers).
// ---------------------------------------------------------------------------
__global__ __launch_bounds__(256) void gemm_bt(
    const ushort* __restrict__ A, const ushort* __restrict__ Bt,
    ushort* __restrict__ C, const float* __restrict__ bias,
    const ushort* __restrict__ resb, const float* __restrict__ resf,
    int M, int N, int K, int relu)
{
    __shared__ __align__(16) ushort As[128 * 32];   // 8 KB
    __shared__ __align__(16) ushort Bs[128 * 32];   // 8 KB
    const int tid  = threadIdx.x;
    const int wave = tid >> 6, lane = tid & 63;
    const int wm = wave >> 1, wn = wave & 1;
    const int qd = lane >> 4, lc = lane & 15;
    const int row0 = blockIdx.y * 128, col0 = blockIdx.x * 128;

    // staging map: thread t covers tile row t/2, cols (t&1)*16 .. +16
    const int srow = tid >> 1;
    const int scol = (tid & 1) * 16;
    const ushort* Ag = A  + (size_t)(row0 + srow) * K + scol;
    const ushort* Bg = Bt + (size_t)(col0 + srow) * K + scol;
    ushort* Asd = &As[srow * 32 + scol];
    ushort* Bsd = &Bs[srow * 32 + scol];

    f32x4 acc[4][4];
#pragma unroll
    for (int i = 0; i < 4; i++)
#pragma unroll
        for (int j = 0; j < 4; j++) acc[i][j] = 0.0f;

    int4 a0 = *(const int4*)(Ag);
    int4 a1 = *(const int4*)(Ag + 8);
    int4 b0 = *(const int4*)(Bg);
    int4 b1 = *(const int4*)(Bg + 8);

    for (int k0 = 0; k0 < K; k0 += 32) {
        __syncthreads();              // prev iteration's LDS readers done
        *(int4*)Asd = a0; *(int4*)(Asd + 8) = a1;
        *(int4*)Bsd = b0; *(int4*)(Bsd + 8) = b1;
        if (k0 + 32 < K) {            // prefetch next chunk (in flight over MFMA)
            a0 = *(const int4*)(Ag + k0 + 32);
            a1 = *(const int4*)(Ag + k0 + 40);
            b0 = *(const int4*)(Bg + k0 + 32);
            b1 = *(const int4*)(Bg + k0 + 40);
        }
        __syncthreads();              // ds_writes visible

        bf16x8 af[4], bfr[4];
#pragma unroll
        for (int mi = 0; mi < 4; mi++)
            af[mi] = *(const bf16x8*)&As[(wm * 64 + mi * 16 + lc) * 32 + qd * 8];
#pragma unroll
        for (int ni = 0; ni < 4; ni++)
            bfr[ni] = *(const bf16x8*)&Bs[(wn * 64 + ni * 16 + lc) * 32 + qd * 8];
#pragma unroll
        for (int mi = 0; mi < 4; mi++)
#pragma unroll
            for (int ni = 0; ni < 4; ni++)
                acc[mi][ni] = __builtin_amdgcn_mfma_f32_16x16x32_bf16(
                    af[mi], bfr[ni], acc[mi][ni], 0, 0, 0);
    }

#pragma unroll
    for (int mi = 0; mi < 4; mi++) {
#pragma unroll
        for (int r = 0; r < 4; r++) {
            int grow = row0 + wm * 64 + mi * 16 + qd * 4 + r;
#pragma unroll
            for (int ni = 0; ni < 4; ni++) {
                int gcol = col0 + wn * 64 + ni * 16 + lc;
                float v = acc[mi][ni][r];
                if (bias) v += bias[gcol];
                if (resb) v += b2f(resb[(size_t)grow * N + gcol]);
                if (resf) v += resf[(size_t)grow * N + gcol];
                if (relu) v = fmaxf(v, 0.0f);
                C[(size_t)grow * N + gcol] = f2b(v);
            }
        }
    }
}

// ---------------------------------------------------------------------------
// GEMM 128x64 tile (N<=768): BK=32, register pipeline. 4 waves on M.
// ---------------------------------------------------------------------------
__global__ __launch_bounds__(256) void gemm_n64(
    const ushort* __restrict__ A, const ushort* __restrict__ Bt,
    ushort* __restrict__ C, const float* __restrict__ bias,
    const ushort* __restrict__ resb, const float* __restrict__ resf,
    int M, int N, int K, int relu)
{
    __shared__ __align__(16) ushort As[128 * 32];   // 8 KB
    __shared__ __align__(16) ushort Bs[64 * 32];    // 4 KB
    const int tid  = threadIdx.x;
    const int wave = tid >> 6, lane = tid & 63;
    const int qd = lane >> 4, lc = lane & 15;
    const int row0 = blockIdx.y * 128, col0 = blockIdx.x * 64;

    // A: thread t -> row t/2, 16-el col (t&1); B: threads 0..127 -> row t/2... 
    // use: A rows 128 x 2 chunks (256 thr); B rows 64 x 2 chunks (128 thr do b).
    const int srow = tid >> 1;
    const int scol = (tid & 1) * 16;
    const ushort* Ag = A + (size_t)(row0 + srow) * K + scol;
    ushort* Asd = &As[srow * 32 + scol];
    const int brow = tid >> 2;             // 0..63
    const int bcol = (tid & 3) * 8;        // 0,8,16,24
    const ushort* Bg = Bt + (size_t)(col0 + brow) * K + bcol;
    ushort* Bsd = &Bs[brow * 32 + bcol];

    f32x4 acc[2][4];
#pragma unroll
    for (int i = 0; i < 2; i++)
#pragma unroll
        for (int j = 0; j < 4; j++) acc[i][j] = 0.0f;

    int4 a0 = *(const int4*)(Ag);
    int4 a1 = *(const int4*)(Ag + 8);
    int4 b0 = *(const int4*)(Bg);

    for (int k0 = 0; k0 < K; k0 += 32) {
        __syncthreads();
        *(int4*)Asd = a0; *(int4*)(Asd + 8) = a1;
        *(int4*)Bsd = b0;
        if (k0 + 32 < K) {
            a0 = *(const int4*)(Ag + k0 + 32);
            a1 = *(const int4*)(Ag + k0 + 40);
            b0 = *(const int4*)(Bg + k0 + 32);
        }
        __syncthreads();

        bf16x8 af[2], bfr[4];
#pragma unroll
        for (int mi = 0; mi < 2; mi++)
            af[mi] = *(const bf16x8*)&As[(wave * 32 + mi * 16 + lc) * 32 + qd * 8];
#pragma unroll
        for (int ni = 0; ni < 4; ni++)
            bfr[ni] = *(const bf16x8*)&Bs[(ni * 16 + lc) * 32 + qd * 8];
#pragma unroll
        for (int mi = 0; mi < 2; mi++)
#pragma unroll
            for (int ni = 0; ni < 4; ni++)
                acc[mi][ni] = __builtin_amdgcn_mfma_f32_16x16x32_bf16(
                    af[mi], bfr[ni], acc[mi][ni], 0, 0, 0);
    }

#pragma unroll
    for (int mi = 0; mi < 2; mi++) {
#pragma unroll
        for (int r = 0; r < 4; r++) {
            int grow = row0 + wave * 32 + mi * 16 + qd * 4 + r;
#pragma unroll
            for (int ni = 0; ni < 4; ni++) {
                int gcol = col0 + ni * 16 + lc;
                float v = acc[mi][ni][r];
                if (bias) v += bias[gcol];
                if (resb) v += b2f(resb[(size_t)grow * N + gcol]);
                if (resf) v += resf[(size_t)grow * N + gcol];
                if (relu) v = fmaxf(v, 0.0f);
                C[(size_t)grow * N + gcol] = f2b(v);
            }
        }
    }
}

// ---------------------------------------------------------------------------
// Fused q2 + kv2 GEMM (both K=384): bx<split -> C1 (N1), else C2 (N2).
// ---------------------------------------------------------------------------
__global__ __launch_bounds__(256) void gemm_dual(
    const ushort* __restrict__ A1, const ushort* __restrict__ B1t,
    ushort* __restrict__ C1, const float* __restrict__ bias1, int N1,
    const ushort* __restrict__ A2, const ushort* __restrict__ B2t,
    ushort* __restrict__ C2, const float* __restrict__ bias2, int N2,
    int split, int K)
{
    __shared__ __align__(16) ushort As[128 * 32];
    __shared__ __align__(16) ushort Bs[64 * 32];
    const int tid  = threadIdx.x;
    const int wave = tid >> 6, lane = tid & 63;
    const int qd = lane >> 4, lc = lane & 15;
    const bool first = (int)blockIdx.x < split;
    const ushort* A  = first ? A1 : A2;
    const ushort* Bt = first ? B1t : B2t;
    ushort* C        = first ? C1 : C2;
    const float* bias = first ? bias1 : bias2;
    const int N      = first ? N1 : N2;
    const int col0   = (first ? blockIdx.x : blockIdx.x - split) * 64;
    const int row0   = blockIdx.y * 128;

    const int srow = tid >> 1;
    const int scol = (tid & 1) * 16;
    const ushort* Ag = A + (size_t)(row0 + srow) * K + scol;
    ushort* Asd = &As[srow * 32 + scol];
    const int brow = tid >> 2;
    const int bcol = (tid & 3) * 8;
    const ushort* Bg = Bt + (size_t)(col0 + brow) * K + bcol;
    ushort* Bsd = &Bs[brow * 32 + bcol];

    f32x4 acc[2][4];
#pragma unroll
    for (int i = 0; i < 2; i++)
#pragma unroll
        for (int j = 0; j < 4; j++) acc[i][j] = 0.0f;

    int4 a0 = *(const int4*)(Ag);
    int4 a1 = *(const int4*)(Ag + 8);
    int4 b0 = *(const int4*)(Bg);

    for (int k0 = 0; k0 < K; k0 += 32) {
        __syncthreads();
        *(int4*)Asd = a0; *(int4*)(Asd + 8) = a1;
        *(int4*)Bsd = b0;
        if (k0 + 32 < K) {
            a0 = *(const int4*)(Ag + k0 + 32);
            a1 = *(const int4*)(Ag + k0 + 40);
            b0 = *(const int4*)(Bg + k0 + 32);
        }
        __syncthreads();

        bf16x8 af[2], bfr[4];
#pragma unroll
        for (int mi = 0; mi < 2; mi++)
            af[mi] = *(const bf16x8*)&As[(wave * 32 + mi * 16 + lc) * 32 + qd * 8];
#pragma unroll
        for (int ni = 0; ni < 4; ni++)
            bfr[ni] = *(const bf16x8*)&Bs[(ni * 16 + lc) * 32 + qd * 8];
#pragma unroll
        for (int mi = 0; mi < 2; mi++)
#pragma unroll
            for (int ni = 0; ni < 4; ni++)
                acc[mi][ni] = __builtin_amdgcn_mfma_f32_16x16x32_bf16(
                    af[mi], bfr[ni], acc[mi][ni], 0, 0, 0);
    }

#pragma unroll
    for (int mi = 0; mi < 2; mi++) {
#pragma unroll
        for (int r = 0; r < 4; r++) {
            int grow = row0 + wave * 32 + mi * 16 + qd * 4 + r;
#pragma unroll
            for (int ni = 0; ni < 4; ni++) {
                int gcol = col0 + ni * 16 + lc;
                float v = acc[mi][ni][r] + bias[gcol];
                C[(size_t)grow * N + gcol] = f2b(v);
            }
        }
    }
}

// ---------------------------------------------------------------------------
// Attention: one block per (b, h, 64-row q tile). Causal tril + softmax.
// ---------------------------------------------------------------------------
__global__ __launch_bounds__(256) void attn(
    const ushort* __restrict__ q, int qstr,
    const ushort* __restrict__ k, int kstr,
    const ushort* __restrict__ v, int vstr,
    ushort* __restrict__ out)
{
    __shared__ __align__(16) ushort Qs[64 * 72];
    __shared__ __align__(16) ushort Kc[64 * 72];
    __shared__ __align__(16) ushort Vc[64 * 72];
    __shared__ __align__(16) ushort Ps[64 * 264];

    const int tid = threadIdx.x;
    const int wave = tid >> 6, lane = tid & 63;
    const int qd = lane >> 4, lc = lane & 15;
    const int b = blockIdx.z, h = blockIdx.y, t0 = blockIdx.x * 64;
    const int hc = h * 64;
    const float scale = 0.051031036307982884f;  // 384^-0.5 (faithful: E, not HS)

    {
        int r = tid >> 2, c = (tid & 3) * 16;
        int4 q0 = *(const int4*)&q[(size_t)(b * 256 + t0 + r) * qstr + hc + c];
        int4 q1 = *(const int4*)&q[(size_t)(b * 256 + t0 + r) * qstr + hc + c + 8];
        *(int4*)&Qs[r * 72 + c] = q0;
        *(int4*)&Qs[r * 72 + c + 8] = q1;
    }

    f32x4 accS[16];
#pragma unroll
    for (int j = 0; j < 16; j++) accS[j] = 0.0f;

    for (int uc = 0; uc < 4; uc++) {
        int r = tid >> 2, c = (tid & 3) * 16;
        int4 k0v = *(const int4*)&k[(size_t)(b * 256 + uc * 64 + r) * kstr + hc + c];
        int4 k1v = *(const int4*)&k[(size_t)(b * 256 + uc * 64 + r) * kstr + hc + c + 8];
        __syncthreads();
        *(int4*)&Kc[r * 72 + c] = k0v;
        *(int4*)&Kc[r * 72 + c + 8] = k1v;
        __syncthreads();
#pragma unroll
        for (int s0 = 0; s0 < 64; s0 += 32) {
            bf16x8 a = *(const bf16x8*)&Qs[(wave * 16 + lc) * 72 + s0 + qd * 8];
#pragma unroll
            for (int ni = 0; ni < 4; ni++) {
                bf16x8 bb = *(const bf16x8*)&Kc[(ni * 16 + lc) * 72 + s0 + qd * 8];
                accS[uc * 4 + ni] =
                    __builtin_amdgcn_mfma_f32_16x16x32_bf16(a, bb, accS[uc * 4 + ni], 0, 0, 0);
            }
        }
    }

#pragma unroll
    for (int rr = 0; rr < 4; rr++) {
        int t = t0 + wave * 16 + qd * 4 + rr;
        float pv[16];
        float mx = -3.0e38f;
#pragma unroll
        for (int j = 0; j < 16; j++) {
            int u = (j >> 2) * 64 + (j & 3) * 16 + lc;
            float s = accS[j][rr] * scale;
            s = (u <= t) ? s : -3.0e38f;
            pv[j] = s;
            mx = fmaxf(mx, s);
        }
#pragma unroll
        for (int m = 1; m < 16; m <<= 1) mx = fmaxf(mx, __shfl_xor(mx, m, 16));
        float sum = 0.0f;
#pragma unroll
        for (int j = 0; j < 16; j++) { float p = __expf(pv[j] - mx); pv[j] = p; sum += p; }
#pragma unroll
        for (int m = 1; m < 16; m <<= 1) sum += __shfl_xor(sum, m, 16);
        float inv = 1.0f / sum;
#pragma unroll
        for (int j = 0; j < 16; j++) {
            int u = (j >> 2) * 64 + (j & 3) * 16 + lc;
            Ps[(wave * 16 + qd * 4 + rr) * 264 + u] = f2b(pv[j] * inv);
        }
    }

    f32x4 accO[4];
#pragma unroll
    for (int j = 0; j < 4; j++) accO[j] = 0.0f;
    for (int uc = 0; uc < 4; uc++) {
        int r = tid >> 2, s0 = (tid & 3) * 16;
        int4 v0 = *(const int4*)&v[(size_t)(b * 256 + uc * 64 + r) * vstr + hc + s0];
        int4 v1 = *(const int4*)&v[(size_t)(b * 256 + uc * 64 + r) * vstr + hc + s0 + 8];
        __syncthreads();
        {
            const ushort* t0p = (const ushort*)&v0;
            const ushort* t1p = (const ushort*)&v1;
#pragma unroll
            for (int j = 0; j < 8; j++) Vc[(s0 + j) * 72 + r] = t0p[j];
#pragma unroll
            for (int j = 0; j < 8; j++) Vc[(s0 + 8 + j) * 72 + r] = t1p[j];
        }
        __syncthreads();
#pragma unroll
        for (int u0 = 0; u0 < 64; u0 += 32) {
            bf16x8 a = *(const bf16x8*)&Ps[(wave * 16 + lc) * 264 + uc * 64 + u0 + qd * 8];
#pragma unroll
            for (int ni = 0; ni < 4; ni++) {
                bf16x8 bb = *(const bf16x8*)&Vc[(ni * 16 + lc) * 72 + u0 + qd * 8];
                accO[ni] = __builtin_amdgcn_mfma_f32_16x16x32_bf16(a, bb, accO[ni], 0, 0, 0);
            }
        }
    }

#pragma unroll
    for (int ni = 0; ni < 4; ni++)
#pragma unroll
        for (int rr = 0; rr < 4; rr++) {
            int t = t0 + wave * 16 + qd * 4 + rr;
            out[(size_t)(b * 256 + t) * 384 + hc + ni * 16 + lc] = f2b(accO[ni][rr]);
        }
}

// ---------------------------------------------------------------------------
// LayerNorm rows of 384. One wave per row. g/be f32; in bf16; out bf16 or f32.
// ---------------------------------------------------------------------------
__global__ __launch_bounds__(256) void lnorm(
    const ushort* __restrict__ in, const float* __restrict__ g,
    const float* __restrict__ be, ushort* __restrict__ outb,
    float* __restrict__ outf)
{
    const int wave = threadIdx.x >> 6, lane = threadIdx.x & 63;
    const int row = blockIdx.x * 4 + wave;
    const ushort* r = in + (size_t)row * 384;
    float x[6], s1 = 0.0f, s2 = 0.0f;
#pragma unroll
    for (int j = 0; j < 6; j++) {
        x[j] = b2f(r[j * 64 + lane]);
        s1 += x[j]; s2 += x[j] * x[j];
    }
#pragma unroll
    for (int m = 1; m < 64; m <<= 1) {
        s1 += __shfl_xor(s1, m, 64);
        s2 += __shfl_xor(s2, m, 64);
    }
    float mean = s1 * (1.0f / 384.0f);
    float var  = s2 * (1.0f / 384.0f) - mean * mean;
    float rstd = rsqrtf(var + 1e-5f);
#pragma unroll
    for (int j = 0; j < 6; j++) {
        float y = (x[j] - mean) * rstd * g[j * 64 + lane] + be[j * 64 + lane];
        if (outb) outb[(size_t)row * 384 + j * 64 + lane] = f2b(y);
        if (outf) outf[(size_t)row * 384 + j * 64 + lane] = y;
    }
}

// ---------------------------------------------------------------------------
// Fused prep: one dispatch does both f32->bf16 converts, both QKV packs,
// all 4 weight transposes, and the bias concat. Branches are block-uniform.
// ---------------------------------------------------------------------------
__device__ __forceinline__ void dev_cvt(const float* in, ushort* out, int blk) {
    size_t i = ((size_t)blk * 256 + threadIdx.x) * 8;
    float4 a = *(const float4*)(in + i);
    float4 b = *(const float4*)(in + i + 4);
    *(int4*)(out + i) = pack8(a, b);
}
__device__ __forceinline__ void dev_transp(const float* in, ushort* out,
                                           int R, int C, int bx, int by,
                                           float (*t)[33]) {
    const int tx = threadIdx.x & 31, ty = threadIdx.x >> 5;
    const int c0 = bx * 32, r0 = by * 32;
#pragma unroll
    for (int i = 0; i < 32; i += 8)
        t[ty + i][tx] = in[(size_t)(r0 + ty + i) * C + c0 + tx];
    __syncthreads();
#pragma unroll
    for (int i = 0; i < 32; i += 8)
        out[(size_t)(c0 + ty + i) * R + r0 + tx] = f2b(t[tx][ty + i]);
}
__device__ __forceinline__ void dev_packqkv(const float* wq, const float* wk,
                                            const float* wv, ushort* Wt,
                                            int blk, float (*t)[33]) {
    const int tx = threadIdx.x & 31, ty = threadIdx.x >> 5;
    const int bx = blk % 12, by = (blk / 12) % 2, bz = blk / 24;
    const int e0 = bx * 32, s0 = by * 32;
    const int seg = bz / 6, h = bz - seg * 6;
    const float* w = (seg == 0) ? wq : (seg == 1) ? wk : wv;
    const float* wh = w + (size_t)h * 384 * 64;
#pragma unroll
    for (int i = 0; i < 32; i += 8)
        t[ty + i][tx] = wh[(size_t)(e0 + ty + i) * 64 + s0 + tx];
    __syncthreads();
    const int nbase = seg * 384 + h * 64 + s0;
#pragma unroll
    for (int i = 0; i < 32; i += 8)
        Wt[(size_t)(nbase + ty + i) * 384 + e0 + tx] = f2b(t[tx][ty + i]);
}

__global__ __launch_bounds__(256) void prep_all(
    const float* __restrict__ x, ushort* __restrict__ xb,
    const float* __restrict__ enc, ushort* __restrict__ encb,
    const float* __restrict__ s1wq, const float* __restrict__ s1wk,
    const float* __restrict__ s1wv, ushort* __restrict__ W1,
    const float* __restrict__ s2wq, const float* __restrict__ s2wk,
    const float* __restrict__ s2wv, ushort* __restrict__ W2,
    const float* __restrict__ s1pw, ushort* __restrict__ pw1t,
    const float* __restrict__ s2pw, ushort* __restrict__ pw2t,
    const float* __restrict__ fw1, ushort* __restrict__ w1t,
    const float* __restrict__ fw2, ushort* __restrict__ w2t,
    const float* __restrict__ s1bq, const float* __restrict__ s1bk,
    const float* __restrict__ s1bv, const float* __restrict__ s2bq,
    const float* __restrict__ s2bk, const float* __restrict__ s2bv,
    float* __restrict__ bias1, float* __restrict__ bias2)
{
    __shared__ float t[32][33];
    int blk = blockIdx.x;
    if (blk < 3072) { dev_cvt(x, xb, blk); return; }
    blk -= 3072;
    if (blk < 3072) { dev_cvt(enc, encb, blk); return; }
    blk -= 3072;
    if (blk < 432) { dev_packqkv(s1wq, s1wk, s1wv, W1, blk, t); return; }
    blk -= 432;
    if (blk < 432) { dev_packqkv(s2wq, s2wk, s2wv, W2, blk, t); return; }
    blk -= 432;
    if (blk < 144) { dev_transp(s1pw, pw1t, 384, 384, blk % 12, blk / 12, t); return; }
    blk -= 144;
    if (blk < 144) { dev_transp(s2pw, pw2t, 384, 384, blk % 12, blk / 12, t); return; }
    blk -= 144;
    if (blk < 576) { dev_transp(fw1, w1t, 384, 1536, blk % 48, blk / 48, t); return; }
    blk -= 576;
    if (blk < 576) { dev_transp(fw2, w2t, 1536, 384, blk % 12, blk / 12, t); return; }
    blk -= 576;
    // bias concat (9 blocks)
    int i = blk * 256 + threadIdx.x;
    if (i >= 2304) return;
    int grp = i / 1152, r = i - grp * 1152;
    int seg = r / 384, nn = r - seg * 384;
    const float* src = grp == 0 ? (seg == 0 ? s1bq : seg == 1 ? s1bk : s1bv)
                                : (seg == 0 ? s2bq : seg == 1 ? s2bk : s2bv);
    (grp == 0 ? bias1 : bias2)[r] = src[nn];
}

// ---------------------------------------------------------------------------
extern "C" void kernel_launch(void* const* d_in, const int* in_sizes, int n_in,
                              void* d_out, int out_size, void* d_ws, size_t ws_size,
                              hipStream_t stream)
{
    const float* enc = (const float*)d_in[0];
    const float* x   = (const float*)d_in[1];
    const float* s1wq = (const float*)d_in[2];  const float* s1bq = (const float*)d_in[3];
    const float* s1wk = (const float*)d_in[4];  const float* s1bk = (const float*)d_in[5];
    const float* s1wv = (const float*)d_in[6];  const float* s1bv = (const float*)d_in[7];
    const float* s1pw = (const float*)d_in[8];  const float* s1pb = (const float*)d_in[9];
    const float* s2wq = (const float*)d_in[10]; const float* s2bq = (const float*)d_in[11];
    const float* s2wk = (const float*)d_in[12]; const float* s2bk = (const float*)d_in[13];
    const float* s2wv = (const float*)d_in[14]; const float* s2bv = (const float*)d_in[15];
    const float* s2pw = (const float*)d_in[16]; const float* s2pb = (const float*)d_in[17];
    const float* fw1 = (const float*)d_in[18];  const float* fb1 = (const float*)d_in[19];
    const float* fw2 = (const float*)d_in[20];  const float* fb2 = (const float*)d_in[21];
    const float* g1 = (const float*)d_in[22];   const float* be1 = (const float*)d_in[23];
    const float* g2 = (const float*)d_in[24];   const float* be2 = (const float*)d_in[25];
    const float* g3 = (const float*)d_in[26];   const float* be3 = (const float*)d_in[27];

    if (ws_size < 80216064u) return;  // proven-available scratch size

    ushort* wsp = (ushort*)d_ws;           // ushort-element offsets
    ushort* qkv1 = wsp;
    ushort* q2   = wsp;
    ushort* kv2  = wsp + 6291456;
    ushort* h1   = wsp;
    ushort* att  = wsp + 18874368;         // [16384,384]; xb shares (dead before attn1)
    ushort* xb   = wsp + 18874368;
    ushort* tmp  = wsp + 25165824;         // [16384,384] pre-LN
    ushort* o1b  = wsp + 31457280;         // [16384,384]
    ushort* W1   = wsp + 37748736;         // [1152,384]
    ushort* W2   = W1 + 442368;
    ushort* pw1t = W2 + 442368;            // [384,384]
    ushort* pw2t = pw1t + 147456;          // [384,384]
    ushort* w1t  = pw2t + 147456;          // [1536,384]
    ushort* w2t  = w1t + 589824;           // [384,1536]

    ushort* encb = (ushort*)d_out;         // dead after kv2 gemm
    ushort* o2b  = (ushort*)d_out;
    float* bias1 = (float*)((ushort*)d_out + 6291456);
    float* bias2 = bias1 + 1152;

    // fused prep (1 dispatch, 8457 blocks)
    prep_all<<<dim3(8457), dim3(256), 0, stream>>>(
        x, xb, enc, encb,
        s1wq, s1wk, s1wv, W1, s2wq, s2wk, s2wv, W2,
        s1pw, pw1t, s2pw, pw2t, fw1, w1t, fw2, w2t,
        s1bq, s1bk, s1bv, s2bq, s2bk, s2bv, bias1, bias2);

    // stage 1
    gemm_bt<<<dim3(9, 128), dim3(256), 0, stream>>>(xb, W1, qkv1, bias1, nullptr, nullptr, 16384, 1152, 384, 0);
    attn<<<dim3(4, 6, 64), dim3(256), 0, stream>>>(qkv1, 1152, qkv1 + 384, 1152, qkv1 + 768, 1152, att);
    gemm_n64<<<dim3(6, 128), dim3(256), 0, stream>>>(att, pw1t, tmp, s1pb, nullptr, x, 16384, 384, 384, 0);
    lnorm<<<dim3(4096), dim3(256), 0, stream>>>(tmp, g1, be1, o1b, nullptr);

    // stage 2 (q2 + kv2 fused)
    gemm_dual<<<dim3(18, 128), dim3(256), 0, stream>>>(
        o1b, W2, q2, bias2, 384,
        encb, W2 + 147456, kv2, bias2 + 384, 768, 6, 384);
    attn<<<dim3(4, 6, 64), dim3(256), 0, stream>>>(q2, 384, kv2, 768, kv2 + 384, 768, att);
    gemm_n64<<<dim3(6, 128), dim3(256), 0, stream>>>(att, pw2t, tmp, s2pb, o1b, nullptr, 16384, 384, 384, 0);
    lnorm<<<dim3(4096), dim3(256), 0, stream>>>(tmp, g2, be2, o2b, nullptr);

    // stage 3
    gemm_bt<<<dim3(12, 128), dim3(256), 0, stream>>>(o2b, w1t, h1, fb1, nullptr, nullptr, 16384, 1536, 384, 1);
    gemm_n64<<<dim3(6, 128), dim3(256), 0, stream>>>(h1, w2t, tmp, fb2, o2b, nullptr, 16384, 384, 1536, 0);
    lnorm<<<dim3(4096), dim3(256), 0, stream>>>(tmp, g3, be3, nullptr, (float*)d_out);
}

// Round 9
// 457.102 us; speedup vs baseline: 1.1762x; 1.0910x over previous
//
#include <hip/hip_runtime.h>

// Internal pipeline bf16 (ushort bits); external inputs/outputs float32.
typedef __attribute__((ext_vector_type(8))) short bf16x8;
typedef __attribute__((ext_vector_type(4))) float f32x4;

__device__ __forceinline__ float b2f(ushort b) {
    union { unsigned int u; float f; } x;
    x.u = ((unsigned int)b) << 16;
    return x.f;
}
__device__ __forceinline__ ushort f2b(float f) {
    union { float f; unsigned int u; } x;
    x.f = f;
    unsigned int r = x.u + 0x7fffu + ((x.u >> 16) & 1u);
    return (ushort)(r >> 16);
}
__device__ __forceinline__ int4 pack8(float4 a, float4 b) {
    union { int4 v; ushort u[8]; } r;
    r.u[0] = f2b(a.x); r.u[1] = f2b(a.y); r.u[2] = f2b(a.z); r.u[3] = f2b(a.w);
    r.u[4] = f2b(b.x); r.u[5] = f2b(b.y); r.u[6] = f2b(b.z); r.u[7] = f2b(b.w);
    return r.v;
}
// cs + resb (both bf16x8 as int4) -> bf16x8
__device__ __forceinline__ int4 add_resb(int4 cs, int4 rs) {
    const ushort* c = (const ushort*)&cs; const ushort* r = (const ushort*)&rs;
    union { int4 v; ushort u[8]; } o;
#pragma unroll
    for (int j = 0; j < 8; j++) o.u[j] = f2b(b2f(c[j]) + b2f(r[j]));
    return o.v;
}
__device__ __forceinline__ int4 add_resf(int4 cs, float4 r0, float4 r1) {
    const ushort* c = (const ushort*)&cs;
    const float* rf0 = (const float*)&r0; const float* rf1 = (const float*)&r1;
    union { int4 v; ushort u[8]; } o;
#pragma unroll
    for (int j = 0; j < 4; j++) o.u[j] = f2b(b2f(c[j]) + rf0[j]);
#pragma unroll
    for (int j = 0; j < 4; j++) o.u[4 + j] = f2b(b2f(c[4 + j]) + rf1[j]);
    return o.v;
}

// ---------------------------------------------------------------------------
// GEMM 128x128 tile (N>=1152). 1-D grid = ncols*128, XCD swizzle: id&7 -> xcd,
// each XCD owns a 16-row-tile stripe (A stays L2-resident per XCD).
// Register-prefetch staging; LDS-staged coalesced epilogue (dwordx4 stores).
// ---------------------------------------------------------------------------
__global__ __launch_bounds__(256) void gemm_bt(
    const ushort* __restrict__ A, const ushort* __restrict__ Bt,
    ushort* __restrict__ C, const float* __restrict__ bias,
    const ushort* __restrict__ resb, const float* __restrict__ resf,
    int N, int K, int relu)
{
    __shared__ __align__(16) ushort As[128 * 32];   // 8 KB
    __shared__ __align__(16) ushort Bs[128 * 32];   // 8 KB
    __shared__ __align__(16) ushort Cs[64 * 132];   // 16.9 KB epilogue staging
    const int tid  = threadIdx.x;
    const int wave = tid >> 6, lane = tid & 63;
    const int wm = wave >> 1, wn = wave & 1;
    const int qd = lane >> 4, lc = lane & 15;
    const int id = blockIdx.x, xcd = id & 7, sub = id >> 3;
    const int row0 = (xcd * 16 + (sub & 15)) * 128;
    const int col0 = (sub >> 4) * 128;

    const int srow = tid >> 1;
    const int scol = (tid & 1) * 16;
    const ushort* Ag = A  + (size_t)(row0 + srow) * K + scol;
    const ushort* Bg = Bt + (size_t)(col0 + srow) * K + scol;
    ushort* Asd = &As[srow * 32 + scol];
    ushort* Bsd = &Bs[srow * 32 + scol];

    f32x4 acc[4][4];
#pragma unroll
    for (int i = 0; i < 4; i++)
#pragma unroll
        for (int j = 0; j < 4; j++) acc[i][j] = 0.0f;

    int4 a0 = *(const int4*)(Ag);
    int4 a1 = *(const int4*)(Ag + 8);
    int4 b0 = *(const int4*)(Bg);
    int4 b1 = *(const int4*)(Bg + 8);

    for (int k0 = 0; k0 < K; k0 += 32) {
        __syncthreads();
        *(int4*)Asd = a0; *(int4*)(Asd + 8) = a1;
        *(int4*)Bsd = b0; *(int4*)(Bsd + 8) = b1;
        if (k0 + 32 < K) {
            a0 = *(const int4*)(Ag + k0 + 32);
            a1 = *(const int4*)(Ag + k0 + 40);
            b0 = *(const int4*)(Bg + k0 + 32);
            b1 = *(const int4*)(Bg + k0 + 40);
        }
        __syncthreads();

        bf16x8 af[4], bfr[4];
#pragma unroll
        for (int mi = 0; mi < 4; mi++)
            af[mi] = *(const bf16x8*)&As[(wm * 64 + mi * 16 + lc) * 32 + qd * 8];
#pragma unroll
        for (int ni = 0; ni < 4; ni++)
            bfr[ni] = *(const bf16x8*)&Bs[(wn * 64 + ni * 16 + lc) * 32 + qd * 8];
#pragma unroll
        for (int mi = 0; mi < 4; mi++)
#pragma unroll
            for (int ni = 0; ni < 4; ni++)
                acc[mi][ni] = __builtin_amdgcn_mfma_f32_16x16x32_bf16(
                    af[mi], bfr[ni], acc[mi][ni], 0, 0, 0);
    }

    // Epilogue: half-tile (64 rows) through LDS, coalesced dwordx4 stores.
#pragma unroll
    for (int half = 0; half < 2; half++) {
        __syncthreads();
        if (wm == half) {
#pragma unroll
            for (int mi = 0; mi < 4; mi++)
#pragma unroll
                for (int r = 0; r < 4; r++) {
                    int lr = mi * 16 + qd * 4 + r;
#pragma unroll
                    for (int ni = 0; ni < 4; ni++) {
                        float v = acc[mi][ni][r];
                        if (bias) v += bias[col0 + wn * 64 + ni * 16 + lc];
                        if (relu) v = fmaxf(v, 0.0f);
                        Cs[lr * 132 + wn * 64 + ni * 16 + lc] = f2b(v);
                    }
                }
        }
        __syncthreads();
        int lr = tid >> 2, cc = (tid & 3) * 32;
        size_t base = (size_t)(row0 + half * 64 + lr) * N + col0 + cc;
#pragma unroll
        for (int i = 0; i < 4; i++) {
            int4 d = *(const int4*)&Cs[lr * 132 + cc + i * 8];
            if (resb) d = add_resb(d, *(const int4*)&resb[base + i * 8]);
            else if (resf) d = add_resf(d, *(const float4*)&resf[base + i * 8],
                                           *(const float4*)&resf[base + i * 8 + 4]);
            *(int4*)&C[base + i * 8] = d;
        }
    }
}

// ---------------------------------------------------------------------------
// GEMM 128x64 tile (N<=768). Same swizzle + LDS epilogue (full tile, 1 pass).
// ---------------------------------------------------------------------------
__global__ __launch_bounds__(256) void gemm_n64(
    const ushort* __restrict__ A, const ushort* __restrict__ Bt,
    ushort* __restrict__ C, const float* __restrict__ bias,
    const ushort* __restrict__ resb, const float* __restrict__ resf,
    int N, int K, int relu)
{
    __shared__ __align__(16) ushort As[128 * 32];   // 8 KB
    __shared__ __align__(16) ushort Bs[64 * 32];    // 4 KB
    __shared__ __align__(16) ushort Cs[128 * 68];   // 17.4 KB
    const int tid  = threadIdx.x;
    const int wave = tid >> 6, lane = tid & 63;
    const int qd = lane >> 4, lc = lane & 15;
    const int id = blockIdx.x, xcd = id & 7, sub = id >> 3;
    const int row0 = (xcd * 16 + (sub & 15)) * 128;
    const int col0 = (sub >> 4) * 64;

    const int srow = tid >> 1;
    const int scol = (tid & 1) * 16;
    const ushort* Ag = A + (size_t)(row0 + srow) * K + scol;
    ushort* Asd = &As[srow * 32 + scol];
    const int brow = tid >> 2;
    const int bcol = (tid & 3) * 8;
    const ushort* Bg = Bt + (size_t)(col0 + brow) * K + bcol;
    ushort* Bsd = &Bs[brow * 32 + bcol];

    f32x4 acc[2][4];
#pragma unroll
    for (int i = 0; i < 2; i++)
#pragma unroll
        for (int j = 0; j < 4; j++) acc[i][j] = 0.0f;

    int4 a0 = *(const int4*)(Ag);
    int4 a1 = *(const int4*)(Ag + 8);
    int4 b0 = *(const int4*)(Bg);

    for (int k0 = 0; k0 < K; k0 += 32) {
        __syncthreads();
        *(int4*)Asd = a0; *(int4*)(Asd + 8) = a1;
        *(int4*)Bsd = b0;
        if (k0 + 32 < K) {
            a0 = *(const int4*)(Ag + k0 + 32);
            a1 = *(const int4*)(Ag + k0 + 40);
            b0 = *(const int4*)(Bg + k0 + 32);
        }
        __syncthreads();

        bf16x8 af[2], bfr[4];
#pragma unroll
        for (int mi = 0; mi < 2; mi++)
            af[mi] = *(const bf16x8*)&As[(wave * 32 + mi * 16 + lc) * 32 + qd * 8];
#pragma unroll
        for (int ni = 0; ni < 4; ni++)
            bfr[ni] = *(const bf16x8*)&Bs[(ni * 16 + lc) * 32 + qd * 8];
#pragma unroll
        for (int mi = 0; mi < 2; mi++)
#pragma unroll
            for (int ni = 0; ni < 4; ni++)
                acc[mi][ni] = __builtin_amdgcn_mfma_f32_16x16x32_bf16(
                    af[mi], bfr[ni], acc[mi][ni], 0, 0, 0);
    }

    __syncthreads();
#pragma unroll
    for (int mi = 0; mi < 2; mi++)
#pragma unroll
        for (int r = 0; r < 4; r++) {
            int lr = wave * 32 + mi * 16 + qd * 4 + r;
#pragma unroll
            for (int ni = 0; ni < 4; ni++) {
                float v = acc[mi][ni][r];
                if (bias) v += bias[col0 + ni * 16 + lc];
                if (relu) v = fmaxf(v, 0.0f);
                Cs[lr * 68 + ni * 16 + lc] = f2b(v);
            }
        }
    __syncthreads();
    {
        int lr = tid >> 1, cc = (tid & 1) * 32;
        size_t base = (size_t)(row0 + lr) * N + col0 + cc;
#pragma unroll
        for (int i = 0; i < 4; i++) {
            int4 d = *(const int4*)&Cs[lr * 68 + cc + i * 8];
            if (resb) d = add_resb(d, *(const int4*)&resb[base + i * 8]);
            else if (resf) d = add_resf(d, *(const float4*)&resf[base + i * 8],
                                           *(const float4*)&resf[base + i * 8 + 4]);
            *(int4*)&C[base + i * 8] = d;
        }
    }
}

// ---------------------------------------------------------------------------
// Fused q2 + kv2 GEMM (both K=384): col tiles 0..5 -> C1(N1=384),
// 6..17 -> C2(N2=768). Swizzled 1-D grid of 18*128 blocks.
// ---------------------------------------------------------------------------
__global__ __launch_bounds__(256) void gemm_dual(
    const ushort* __restrict__ A1, const ushort* __restrict__ B1t,
    ushort* __restrict__ C1, const float* __restrict__ bias1, int N1,
    const ushort* __restrict__ A2, const ushort* __restrict__ B2t,
    ushort* __restrict__ C2, const float* __restrict__ bias2, int N2,
    int split, int K)
{
    __shared__ __align__(16) ushort As[128 * 32];
    __shared__ __align__(16) ushort Bs[64 * 32];
    __shared__ __align__(16) ushort Cs[128 * 68];
    const int tid  = threadIdx.x;
    const int wave = tid >> 6, lane = tid & 63;
    const int qd = lane >> 4, lc = lane & 15;
    const int id = blockIdx.x, xcd = id & 7, sub = id >> 3;
    const int row0 = (xcd * 16 + (sub & 15)) * 128;
    int ct = sub >> 4;
    const bool first = ct < split;
    const ushort* A  = first ? A1 : A2;
    const ushort* Bt = first ? B1t : B2t;
    ushort* C        = first ? C1 : C2;
    const float* bias = first ? bias1 : bias2;
    const int N      = first ? N1 : N2;
    const int col0   = (first ? ct : ct - split) * 64;

    const int srow = tid >> 1;
    const int scol = (tid & 1) * 16;
    const ushort* Ag = A + (size_t)(row0 + srow) * K + scol;
    ushort* Asd = &As[srow * 32 + scol];
    const int brow = tid >> 2;
    const int bcol = (tid & 3) * 8;
    const ushort* Bg = Bt + (size_t)(col0 + brow) * K + bcol;
    ushort* Bsd = &Bs[brow * 32 + bcol];

    f32x4 acc[2][4];
#pragma unroll
    for (int i = 0; i < 2; i++)
#pragma unroll
        for (int j = 0; j < 4; j++) acc[i][j] = 0.0f;

    int4 a0 = *(const int4*)(Ag);
    int4 a1 = *(const int4*)(Ag + 8);
    int4 b0 = *(const int4*)(Bg);

    for (int k0 = 0; k0 < K; k0 += 32) {
        __syncthreads();
        *(int4*)Asd = a0; *(int4*)(Asd + 8) = a1;
        *(int4*)Bsd = b0;
        if (k0 + 32 < K) {
            a0 = *(const int4*)(Ag + k0 + 32);
            a1 = *(const int4*)(Ag + k0 + 40);
            b0 = *(const int4*)(Bg + k0 + 32);
        }
        __syncthreads();

        bf16x8 af[2], bfr[4];
#pragma unroll
        for (int mi = 0; mi < 2; mi++)
            af[mi] = *(const bf16x8*)&As[(wave * 32 + mi * 16 + lc) * 32 + qd * 8];
#pragma unroll
        for (int ni = 0; ni < 4; ni++)
            bfr[ni] = *(const bf16x8*)&Bs[(ni * 16 + lc) * 32 + qd * 8];
#pragma unroll
        for (int mi = 0; mi < 2; mi++)
#pragma unroll
            for (int ni = 0; ni < 4; ni++)
                acc[mi][ni] = __builtin_amdgcn_mfma_f32_16x16x32_bf16(
                    af[mi], bfr[ni], acc[mi][ni], 0, 0, 0);
    }

    __syncthreads();
#pragma unroll
    for (int mi = 0; mi < 2; mi++)
#pragma unroll
        for (int r = 0; r < 4; r++) {
            int lr = wave * 32 + mi * 16 + qd * 4 + r;
#pragma unroll
            for (int ni = 0; ni < 4; ni++)
                Cs[lr * 68 + ni * 16 + lc] = f2b(acc[mi][ni][r] + bias[col0 + ni * 16 + lc]);
        }
    __syncthreads();
    {
        int lr = tid >> 1, cc = (tid & 1) * 32;
        size_t base = (size_t)(row0 + lr) * N + col0 + cc;
#pragma unroll
        for (int i = 0; i < 4; i++)
            *(int4*)&C[base + i * 8] = *(const int4*)&Cs[lr * 68 + cc + i * 8];
    }
}

// ---------------------------------------------------------------------------
// Attention: one block per (b, h, 64-row q tile). Causal tril + softmax.
// ---------------------------------------------------------------------------
__global__ __launch_bounds__(256) void attn(
    const ushort* __restrict__ q, int qstr,
    const ushort* __restrict__ k, int kstr,
    const ushort* __restrict__ v, int vstr,
    ushort* __restrict__ out)
{
    __shared__ __align__(16) ushort Qs[64 * 72];
    __shared__ __align__(16) ushort Kc[64 * 72];
    __shared__ __align__(16) ushort Vc[64 * 72];
    __shared__ __align__(16) ushort Ps[64 * 264];

    const int tid = threadIdx.x;
    const int wave = tid >> 6, lane = tid & 63;
    const int qd = lane >> 4, lc = lane & 15;
    const int b = blockIdx.z, h = blockIdx.y, t0 = blockIdx.x * 64;
    const int hc = h * 64;
    const float scale = 0.051031036307982884f;  // 384^-0.5 (faithful: E, not HS)

    {
        int r = tid >> 2, c = (tid & 3) * 16;
        int4 q0 = *(const int4*)&q[(size_t)(b * 256 + t0 + r) * qstr + hc + c];
        int4 q1 = *(const int4*)&q[(size_t)(b * 256 + t0 + r) * qstr + hc + c + 8];
        *(int4*)&Qs[r * 72 + c] = q0;
        *(int4*)&Qs[r * 72 + c + 8] = q1;
    }

    f32x4 accS[16];
#pragma unroll
    for (int j = 0; j < 16; j++) accS[j] = 0.0f;

    for (int uc = 0; uc < 4; uc++) {
        int r = tid >> 2, c = (tid & 3) * 16;
        int4 k0v = *(const int4*)&k[(size_t)(b * 256 + uc * 64 + r) * kstr + hc + c];
        int4 k1v = *(const int4*)&k[(size_t)(b * 256 + uc * 64 + r) * kstr + hc + c + 8];
        __syncthreads();
        *(int4*)&Kc[r * 72 + c] = k0v;
        *(int4*)&Kc[r * 72 + c + 8] = k1v;
        __syncthreads();
#pragma unroll
        for (int s0 = 0; s0 < 64; s0 += 32) {
            bf16x8 a = *(const bf16x8*)&Qs[(wave * 16 + lc) * 72 + s0 + qd * 8];
#pragma unroll
            for (int ni = 0; ni < 4; ni++) {
                bf16x8 bb = *(const bf16x8*)&Kc[(ni * 16 + lc) * 72 + s0 + qd * 8];
                accS[uc * 4 + ni] =
                    __builtin_amdgcn_mfma_f32_16x16x32_bf16(a, bb, accS[uc * 4 + ni], 0, 0, 0);
            }
        }
    }

#pragma unroll
    for (int rr = 0; rr < 4; rr++) {
        int t = t0 + wave * 16 + qd * 4 + rr;
        float pv[16];
        float mx = -3.0e38f;
#pragma unroll
        for (int j = 0; j < 16; j++) {
            int u = (j >> 2) * 64 + (j & 3) * 16 + lc;
            float s = accS[j][rr] * scale;
            s = (u <= t) ? s : -3.0e38f;
            pv[j] = s;
            mx = fmaxf(mx, s);
        }
#pragma unroll
        for (int m = 1; m < 16; m <<= 1) mx = fmaxf(mx, __shfl_xor(mx, m, 16));
        float sum = 0.0f;
#pragma unroll
        for (int j = 0; j < 16; j++) { float p = __expf(pv[j] - mx); pv[j] = p; sum += p; }
#pragma unroll
        for (int m = 1; m < 16; m <<= 1) sum += __shfl_xor(sum, m, 16);
        float inv = 1.0f / sum;
#pragma unroll
        for (int j = 0; j < 16; j++) {
            int u = (j >> 2) * 64 + (j & 3) * 16 + lc;
            Ps[(wave * 16 + qd * 4 + rr) * 264 + u] = f2b(pv[j] * inv);
        }
    }

    f32x4 accO[4];
#pragma unroll
    for (int j = 0; j < 4; j++) accO[j] = 0.0f;
    for (int uc = 0; uc < 4; uc++) {
        int r = tid >> 2, s0 = (tid & 3) * 16;
        int4 v0 = *(const int4*)&v[(size_t)(b * 256 + uc * 64 + r) * vstr + hc + s0];
        int4 v1 = *(const int4*)&v[(size_t)(b * 256 + uc * 64 + r) * vstr + hc + s0 + 8];
        __syncthreads();
        {
            const ushort* t0p = (const ushort*)&v0;
            const ushort* t1p = (const ushort*)&v1;
#pragma unroll
            for (int j = 0; j < 8; j++) Vc[(s0 + j) * 72 + r] = t0p[j];
#pragma unroll
            for (int j = 0; j < 8; j++) Vc[(s0 + 8 + j) * 72 + r] = t1p[j];
        }
        __syncthreads();
#pragma unroll
        for (int u0 = 0; u0 < 64; u0 += 32) {
            bf16x8 a = *(const bf16x8*)&Ps[(wave * 16 + lc) * 264 + uc * 64 + u0 + qd * 8];
#pragma unroll
            for (int ni = 0; ni < 4; ni++) {
                bf16x8 bb = *(const bf16x8*)&Vc[(ni * 16 + lc) * 72 + u0 + qd * 8];
                accO[ni] = __builtin_amdgcn_mfma_f32_16x16x32_bf16(a, bb, accO[ni], 0, 0, 0);
            }
        }
    }

#pragma unroll
    for (int ni = 0; ni < 4; ni++)
#pragma unroll
        for (int rr = 0; rr < 4; rr++) {
            int t = t0 + wave * 16 + qd * 4 + rr;
            out[(size_t)(b * 256 + t) * 384 + hc + ni * 16 + lc] = f2b(accO[ni][rr]);
        }
}

// ---------------------------------------------------------------------------
// LayerNorm rows of 384. One wave per row. g/be f32; in bf16; out bf16 or f32.
// ---------------------------------------------------------------------------
__global__ __launch_bounds__(256) void lnorm(
    const ushort* __restrict__ in, const float* __restrict__ g,
    const float* __restrict__ be, ushort* __restrict__ outb,
    float* __restrict__ outf)
{
    const int wave = threadIdx.x >> 6, lane = threadIdx.x & 63;
    const int row = blockIdx.x * 4 + wave;
    const ushort* r = in + (size_t)row * 384;
    float x[6], s1 = 0.0f, s2 = 0.0f;
#pragma unroll
    for (int j = 0; j < 6; j++) {
        x[j] = b2f(r[j * 64 + lane]);
        s1 += x[j]; s2 += x[j] * x[j];
    }
#pragma unroll
    for (int m = 1; m < 64; m <<= 1) {
        s1 += __shfl_xor(s1, m, 64);
        s2 += __shfl_xor(s2, m, 64);
    }
    float mean = s1 * (1.0f / 384.0f);
    float var  = s2 * (1.0f / 384.0f) - mean * mean;
    float rstd = rsqrtf(var + 1e-5f);
#pragma unroll
    for (int j = 0; j < 6; j++) {
        float y = (x[j] - mean) * rstd * g[j * 64 + lane] + be[j * 64 + lane];
        if (outb) outb[(size_t)row * 384 + j * 64 + lane] = f2b(y);
        if (outf) outf[(size_t)row * 384 + j * 64 + lane] = y;
    }
}

// ---------------------------------------------------------------------------
// Fused prep (unchanged from r8).
// ---------------------------------------------------------------------------
__device__ __forceinline__ void dev_cvt(const float* in, ushort* out, int blk) {
    size_t i = ((size_t)blk * 256 + threadIdx.x) * 8;
    float4 a = *(const float4*)(in + i);
    float4 b = *(const float4*)(in + i + 4);
    *(int4*)(out + i) = pack8(a, b);
}
__device__ __forceinline__ void dev_transp(const float* in, ushort* out,
                                           int R, int C, int bx, int by,
                                           float (*t)[33]) {
    const int tx = threadIdx.x & 31, ty = threadIdx.x >> 5;
    const int c0 = bx * 32, r0 = by * 32;
#pragma unroll
    for (int i = 0; i < 32; i += 8)
        t[ty + i][tx] = in[(size_t)(r0 + ty + i) * C + c0 + tx];
    __syncthreads();
#pragma unroll
    for (int i = 0; i < 32; i += 8)
        out[(size_t)(c0 + ty + i) * R + r0 + tx] = f2b(t[tx][ty + i]);
}
__device__ __forceinline__ void dev_packqkv(const float* wq, const float* wk,
                                            const float* wv, ushort* Wt,
                                            int blk, float (*t)[33]) {
    const int tx = threadIdx.x & 31, ty = threadIdx.x >> 5;
    const int bx = blk % 12, by = (blk / 12) % 2, bz = blk / 24;
    const int e0 = bx * 32, s0 = by * 32;
    const int seg = bz / 6, h = bz - seg * 6;
    const float* w = (seg == 0) ? wq : (seg == 1) ? wk : wv;
    const float* wh = w + (size_t)h * 384 * 64;
#pragma unroll
    for (int i = 0; i < 32; i += 8)
        t[ty + i][tx] = wh[(size_t)(e0 + ty + i) * 64 + s0 + tx];
    __syncthreads();
    const int nbase = seg * 384 + h * 64 + s0;
#pragma unroll
    for (int i = 0; i < 32; i += 8)
        Wt[(size_t)(nbase + ty + i) * 384 + e0 + tx] = f2b(t[tx][ty + i]);
}

__global__ __launch_bounds__(256) void prep_all(
    const float* __restrict__ x, ushort* __restrict__ xb,
    const float* __restrict__ enc, ushort* __restrict__ encb,
    const float* __restrict__ s1wq, const float* __restrict__ s1wk,
    const float* __restrict__ s1wv, ushort* __restrict__ W1,
    const float* __restrict__ s2wq, const float* __restrict__ s2wk,
    const float* __restrict__ s2wv, ushort* __restrict__ W2,
    const float* __restrict__ s1pw, ushort* __restrict__ pw1t,
    const float* __restrict__ s2pw, ushort* __restrict__ pw2t,
    const float* __restrict__ fw1, ushort* __restrict__ w1t,
    const float* __restrict__ fw2, ushort* __restrict__ w2t,
    const float* __restrict__ s1bq, const float* __restrict__ s1bk,
    const float* __restrict__ s1bv, const float* __restrict__ s2bq,
    const float* __restrict__ s2bk, const float* __restrict__ s2bv,
    float* __restrict__ bias1, float* __restrict__ bias2)
{
    __shared__ float t[32][33];
    int blk = blockIdx.x;
    if (blk < 3072) { dev_cvt(x, xb, blk); return; }
    blk -= 3072;
    if (blk < 3072) { dev_cvt(enc, encb, blk); return; }
    blk -= 3072;
    if (blk < 432) { dev_packqkv(s1wq, s1wk, s1wv, W1, blk, t); return; }
    blk -= 432;
    if (blk < 432) { dev_packqkv(s2wq, s2wk, s2wv, W2, blk, t); return; }
    blk -= 432;
    if (blk < 144) { dev_transp(s1pw, pw1t, 384, 384, blk % 12, blk / 12, t); return; }
    blk -= 144;
    if (blk < 144) { dev_transp(s2pw, pw2t, 384, 384, blk % 12, blk / 12, t); return; }
    blk -= 144;
    if (blk < 576) { dev_transp(fw1, w1t, 384, 1536, blk % 48, blk / 48, t); return; }
    blk -= 576;
    if (blk < 576) { dev_transp(fw2, w2t, 1536, 384, blk % 12, blk / 12, t); return; }
    blk -= 576;
    int i = blk * 256 + threadIdx.x;
    if (i >= 2304) return;
    int grp = i / 1152, r = i - grp * 1152;
    int seg = r / 384, nn = r - seg * 384;
    const float* src = grp == 0 ? (seg == 0 ? s1bq : seg == 1 ? s1bk : s1bv)
                                : (seg == 0 ? s2bq : seg == 1 ? s2bk : s2bv);
    (grp == 0 ? bias1 : bias2)[r] = src[nn];
}

// ---------------------------------------------------------------------------
extern "C" void kernel_launch(void* const* d_in, const int* in_sizes, int n_in,
                              void* d_out, int out_size, void* d_ws, size_t ws_size,
                              hipStream_t stream)
{
    const float* enc = (const float*)d_in[0];
    const float* x   = (const float*)d_in[1];
    const float* s1wq = (const float*)d_in[2];  const float* s1bq = (const float*)d_in[3];
    const float* s1wk = (const float*)d_in[4];  const float* s1bk = (const float*)d_in[5];
    const float* s1wv = (const float*)d_in[6];  const float* s1bv = (const float*)d_in[7];
    const float* s1pw = (const float*)d_in[8];  const float* s1pb = (const float*)d_in[9];
    const float* s2wq = (const float*)d_in[10]; const float* s2bq = (const float*)d_in[11];
    const float* s2wk = (const float*)d_in[12]; const float* s2bk = (const float*)d_in[13];
    const float* s2wv = (const float*)d_in[14]; const float* s2bv = (const float*)d_in[15];
    const float* s2pw = (const float*)d_in[16]; const float* s2pb = (const float*)d_in[17];
    const float* fw1 = (const float*)d_in[18];  const float* fb1 = (const float*)d_in[19];
    const float* fw2 = (const float*)d_in[20];  const float* fb2 = (const float*)d_in[21];
    const float* g1 = (const float*)d_in[22];   const float* be1 = (const float*)d_in[23];
    const float* g2 = (const float*)d_in[24];   const float* be2 = (const float*)d_in[25];
    const float* g3 = (const float*)d_in[26];   const float* be3 = (const float*)d_in[27];

    if (ws_size < 80216064u) return;  // proven-available scratch size

    ushort* wsp = (ushort*)d_ws;           // ushort-element offsets
    ushort* qkv1 = wsp;
    ushort* q2   = wsp;
    ushort* kv2  = wsp + 6291456;
    ushort* h1   = wsp;
    ushort* att  = wsp + 18874368;         // [16384,384]; xb shares (dead before attn1)
    ushort* xb   = wsp + 18874368;
    ushort* tmp  = wsp + 25165824;         // [16384,384] pre-LN
    ushort* o1b  = wsp + 31457280;         // [16384,384]
    ushort* W1   = wsp + 37748736;         // [1152,384]
    ushort* W2   = W1 + 442368;
    ushort* pw1t = W2 + 442368;            // [384,384]
    ushort* pw2t = pw1t + 147456;          // [384,384]
    ushort* w1t  = pw2t + 147456;          // [1536,384]
    ushort* w2t  = w1t + 589824;           // [384,1536]

    ushort* encb = (ushort*)d_out;         // dead after kv2 gemm
    ushort* o2b  = (ushort*)d_out;
    float* bias1 = (float*)((ushort*)d_out + 6291456);
    float* bias2 = bias1 + 1152;

    // fused prep (1 dispatch)
    prep_all<<<dim3(8457), dim3(256), 0, stream>>>(
        x, xb, enc, encb,
        s1wq, s1wk, s1wv, W1, s2wq, s2wk, s2wv, W2,
        s1pw, pw1t, s2pw, pw2t, fw1, w1t, fw2, w2t,
        s1bq, s1bk, s1bv, s2bq, s2bk, s2bv, bias1, bias2);

    // stage 1
    gemm_bt<<<dim3(9 * 128), dim3(256), 0, stream>>>(xb, W1, qkv1, bias1, nullptr, nullptr, 1152, 384, 0);
    attn<<<dim3(4, 6, 64), dim3(256), 0, stream>>>(qkv1, 1152, qkv1 + 384, 1152, qkv1 + 768, 1152, att);
    gemm_n64<<<dim3(6 * 128), dim3(256), 0, stream>>>(att, pw1t, tmp, s1pb, nullptr, x, 384, 384, 0);
    lnorm<<<dim3(4096), dim3(256), 0, stream>>>(tmp, g1, be1, o1b, nullptr);

    // stage 2 (q2 + kv2 fused)
    gemm_dual<<<dim3(18 * 128), dim3(256), 0, stream>>>(
        o1b, W2, q2, bias2, 384,
        encb, W2 + 147456, kv2, bias2 + 384, 768, 6, 384);
    attn<<<dim3(4, 6, 64), dim3(256), 0, stream>>>(q2, 384, kv2, 768, kv2 + 384, 768, att);
    gemm_n64<<<dim3(6 * 128), dim3(256), 0, stream>>>(att, pw2t, tmp, s2pb, o1b, nullptr, 384, 384, 0);
    lnorm<<<dim3(4096), dim3(256), 0, stream>>>(tmp, g2, be2, o2b, nullptr);

    // stage 3
    gemm_bt<<<dim3(12 * 128), dim3(256), 0, stream>>>(o2b, w1t, h1, fb1, nullptr, nullptr, 1536, 384, 1);
    gemm_n64<<<dim3(6 * 128), dim3(256), 0, stream>>>(h1, w2t, tmp, fb2, o2b, nullptr, 384, 1536, 0);
    lnorm<<<dim3(4096), dim3(256), 0, stream>>>(tmp, g3, be3, nullptr, (float*)d_out);
}